// Round 1
// baseline (352.429 us; speedup 1.0000x reference)
//
#include <hip/hip_runtime.h>

// MaxUnpooling2D: B=16, H=128, W=128, C=64, S=2 -> out (16,256,256,64) f32.
// Mask construction guarantees each pooled element scatters into its OWN 2x2
// window (disjoint windows), so scatter-add == gather.
//
// V4: OUTPUT-major mapping for perfectly contiguous stores.
// Thread owns one output (x, c4) column-pair: it loads the single input
// float4 group (b, h=y/2, w=x/2, c4) feeding that column, and writes the
// two output groups (b, 2h, x, c4) and (b, 2h+1, x, c4).
//  - Store instruction across a wave: 64 lanes x 16 B = 1 KiB fully
//    contiguous, line-aligned (same per-instruction pattern as the 6.3 TB/s
//    fill). vs V3's 4x256B scattered chunks per instruction.
//  - Load instruction: lanes at x and x+1 duplicate the same input address;
//    the coalescer collapses them -> 512 B fetched per instruction, each
//    input byte fetched exactly once from HBM.
//  - Plain (cached) loads for inputs; nontemporal stores (zero reuse).
// Every output element written exactly once -> no memset, no atomics.

typedef float f32x4 __attribute__((ext_vector_type(4)));
typedef int   i32x4 __attribute__((ext_vector_type(4)));

__global__ __launch_bounds__(256) void MaxUnpooling2D_13589276524630_kernel(
        const f32x4* __restrict__ upd,   // (B,H,W,C) as 4-float groups
        const i32x4* __restrict__ msk,   // (B,H,W,C) as 4-int groups
        f32x4*       __restrict__ out)   // (B,Ho,Wo,C) as 4-float groups
{
    // p indexes (b, h, x, c4): 16*128*256*16 = 8,388,608 column-pairs.
    // 4 per thread, 256 threads/block -> 8192 blocks.
    const int p0 = blockIdx.x * (4 * 256) + threadIdx.x;

    f32x4 u[4];
    i32x4 m[4];
    // Issue all loads up front (deep per-wave load queue for latency hiding).
#pragma unroll
    for (int j = 0; j < 4; ++j) {
        const int p  = p0 + j * 256;
        const int c4 = p & 15;            // channel group 0..15
        const int x  = (p >> 4) & 255;    // output column 0..255
        const int bh = p >> 12;           // b*128 + h
        // input group (b,h,w=x>>1,c4): ((b*128+h)*128 + w)*16 + c4
        const int in_g = (bh << 11) | ((x >> 1) << 4) | c4;
        u[j] = upd[in_g];
        m[j] = msk[in_g];
    }

#pragma unroll
    for (int j = 0; j < 4; ++j) {
        const int p  = p0 + j * 256;
        const int c4 = p & 15;
        const int x  = (p >> 4) & 255;
        const int h  = (p >> 12) & 127;
        const int b  = p >> 19;

        // Per-batch flat float index of output element (y=2h, x, c=c4*4):
        // fb = (y*256 + x)*64 + c
        const int fb0 = (((h << 9) | x) << 6) | (c4 << 2);
        const int fb1 = fb0 + 256 * 64;           // next output row (y=2h+1)

        f32x4 v0, v1;
        v0.x = (m[j].x == fb0    ) ? u[j].x : 0.0f;
        v0.y = (m[j].y == fb0 + 1) ? u[j].y : 0.0f;
        v0.z = (m[j].z == fb0 + 2) ? u[j].z : 0.0f;
        v0.w = (m[j].w == fb0 + 3) ? u[j].w : 0.0f;
        v1.x = (m[j].x == fb1    ) ? u[j].x : 0.0f;
        v1.y = (m[j].y == fb1 + 1) ? u[j].y : 0.0f;
        v1.z = (m[j].z == fb1 + 2) ? u[j].z : 0.0f;
        v1.w = (m[j].w == fb1 + 3) ? u[j].w : 0.0f;

        // Output float4-group index: (b*2^22 + fb)/4
        const int og0 = ((b << 22) + fb0) >> 2;
        __builtin_nontemporal_store(v0, &out[og0]);
        __builtin_nontemporal_store(v1, &out[og0 + (256 * 64 / 4)]);
    }
}

extern "C" void kernel_launch(void* const* d_in, const int* in_sizes, int n_in,
                              void* d_out, int out_size, void* d_ws, size_t ws_size,
                              hipStream_t stream) {
    const f32x4* upd = (const f32x4*)d_in[0];
    const i32x4* msk = (const i32x4*)d_in[1];
    f32x4*       out = (f32x4*)d_out;

    const int n_pairs = 16 * 128 * 256 * 16;   // 8,388,608 (b,h,x,c4) pairs
    const int block = 256;
    const int grid = n_pairs / (block * 4);    // 8192 blocks

    MaxUnpooling2D_13589276524630_kernel<<<grid, block, 0, stream>>>(upd, msk, out);
}

// Round 2
// 349.127 us; speedup vs baseline: 1.0095x; 1.0095x over previous
//
#include <hip/hip_runtime.h>

// MaxUnpooling2D: B=16, H=128, W=128, C=64, S=2 -> out (16,256,256,64) f32.
// Mask construction guarantees each pooled element scatters into its OWN 2x2
// window (disjoint windows), so scatter-add == gather.
//
// V5: V4 (output-major, fully contiguous 1 KiB-per-instruction stores) with
// PLAIN stores instead of nontemporal.
// Rationale: V3 (scattered NT stores) == V4 (contiguous NT stores) == ~160us
// kernel, while the harness's fillBufferAligned (plain stores, same 6.3 TB/s
// write stream shape) hits 78-82% of HBM peak. The one config shared by both
// slow versions and absent from the fast fill is the nt flag on stores.
// nt = L2/MALL no-allocate hint; for a streaming write this forgoes L2
// write-back aggregation. Single-variable A/B: drop nt, change nothing else.
// Every output element written exactly once -> no memset, no atomics.

typedef float f32x4 __attribute__((ext_vector_type(4)));
typedef int   i32x4 __attribute__((ext_vector_type(4)));

__global__ __launch_bounds__(256) void MaxUnpooling2D_13589276524630_kernel(
        const f32x4* __restrict__ upd,   // (B,H,W,C) as 4-float groups
        const i32x4* __restrict__ msk,   // (B,H,W,C) as 4-int groups
        f32x4*       __restrict__ out)   // (B,Ho,Wo,C) as 4-float groups
{
    // p indexes (b, h, x, c4): 16*128*256*16 = 8,388,608 column-pairs.
    // 4 per thread, 256 threads/block -> 8192 blocks.
    const int p0 = blockIdx.x * (4 * 256) + threadIdx.x;

    f32x4 u[4];
    i32x4 m[4];
    // Issue all loads up front (deep per-wave load queue for latency hiding).
#pragma unroll
    for (int j = 0; j < 4; ++j) {
        const int p  = p0 + j * 256;
        const int c4 = p & 15;            // channel group 0..15
        const int x  = (p >> 4) & 255;    // output column 0..255
        const int bh = p >> 12;           // b*128 + h
        // input group (b,h,w=x>>1,c4): ((b*128+h)*128 + w)*16 + c4
        const int in_g = (bh << 11) | ((x >> 1) << 4) | c4;
        u[j] = upd[in_g];
        m[j] = msk[in_g];
    }

#pragma unroll
    for (int j = 0; j < 4; ++j) {
        const int p  = p0 + j * 256;
        const int c4 = p & 15;
        const int x  = (p >> 4) & 255;
        const int h  = (p >> 12) & 127;
        const int b  = p >> 19;

        // Per-batch flat float index of output element (y=2h, x, c=c4*4):
        // fb = (y*256 + x)*64 + c
        const int fb0 = (((h << 9) | x) << 6) | (c4 << 2);
        const int fb1 = fb0 + 256 * 64;           // next output row (y=2h+1)

        f32x4 v0, v1;
        v0.x = (m[j].x == fb0    ) ? u[j].x : 0.0f;
        v0.y = (m[j].y == fb0 + 1) ? u[j].y : 0.0f;
        v0.z = (m[j].z == fb0 + 2) ? u[j].z : 0.0f;
        v0.w = (m[j].w == fb0 + 3) ? u[j].w : 0.0f;
        v1.x = (m[j].x == fb1    ) ? u[j].x : 0.0f;
        v1.y = (m[j].y == fb1 + 1) ? u[j].y : 0.0f;
        v1.z = (m[j].z == fb1 + 2) ? u[j].z : 0.0f;
        v1.w = (m[j].w == fb1 + 3) ? u[j].w : 0.0f;

        // Output float4-group index: (b*2^22 + fb)/4
        const int og0 = ((b << 22) + fb0) >> 2;
        out[og0]                 = v0;   // plain store: L2 write-back path
        out[og0 + (256*64/4)]    = v1;   // (the path the 6.3 TB/s fill uses)
    }
}

extern "C" void kernel_launch(void* const* d_in, const int* in_sizes, int n_in,
                              void* d_out, int out_size, void* d_ws, size_t ws_size,
                              hipStream_t stream) {
    const f32x4* upd = (const f32x4*)d_in[0];
    const i32x4* msk = (const i32x4*)d_in[1];
    f32x4*       out = (f32x4*)d_out;

    const int n_pairs = 16 * 128 * 256 * 16;   // 8,388,608 (b,h,x,c4) pairs
    const int block = 256;
    const int grid = n_pairs / (block * 4);    // 8192 blocks

    MaxUnpooling2D_13589276524630_kernel<<<grid, block, 0, stream>>>(upd, msk, out);
}